// Round 18
// baseline (114.195 us; speedup 1.0000x reference)
//
#include <hip/hip_runtime.h>

// MeanAggregator on MI355X.
// k_init -> k_mlp_place (merged, 32KB LDS: sW1-as-sT only; GEMM2 B from global) -> k_aggregate.

constexpr int D = 128;
constexpr int MAXDEG = 24;
constexpr int OVF_CAP = 131072;

typedef __attribute__((ext_vector_type(8))) short short8;
typedef __attribute__((ext_vector_type(4))) float f32x4;
struct ushort8_s { unsigned short v[8]; };

__device__ __forceinline__ unsigned short f2bf(float x) {
    unsigned int u = __float_as_uint(x);
    u += 0x7fffu + ((u >> 16) & 1u);
    return (unsigned short)(u >> 16);
}
__device__ __forceinline__ float bflo(unsigned int u) { return __uint_as_float(u << 16); }
__device__ __forceinline__ float bfhi(unsigned int u) { return __uint_as_float(u & 0xffff0000u); }
__device__ __forceinline__ float fast_tanh(float x) {
    float e = exp2f(x * 2.885390081777927f);
    return fmaf(-2.0f, __builtin_amdgcn_rcpf(e + 1.0f), 1.0f);
}
// swizzled byte offset inside a [128 rows x 256 B] tile
__device__ __forceinline__ int swz(int row, int kbyte) {
    return (row * 256 + kbyte) ^ ((row & 7) << 4);
}

// ---- K0: W1 -> bf16 PRE-SWIZZLED image; W2 -> bf16 [n][k] row-major (blocks 0..63)
//      | zero packed+ovf_cnt (rest) ----
__global__ __launch_bounds__(256) void k_init(const float* __restrict__ W1,
                                              const float* __restrict__ W2,
                                              unsigned short* __restrict__ Wt1s,
                                              unsigned short* __restrict__ Wt2t,
                                              int* __restrict__ zbase, int zv4) {
    int b = blockIdx.x;
    if (b < 64) {
        int t = b * 256 + threadIdx.x;  // t = k*D + nn (coalesced read)
        int k = t >> 7, nn = t & 127;
        Wt1s[swz(nn, k * 2) >> 1] = f2bf(W1[t]);   // swizzled image for LDS staging
        Wt2t[nn * D + k] = f2bf(W2[t]);            // plain transposed [n][k] for direct loads
    } else {
        int i = (b - 64) * 256 + threadIdx.x;
        if (i < zv4) ((int4*)zbase)[i] = make_int4(0, 0, 0, 0);
    }
}

// ---- K1: every block = MLP (128 rows, 8 waves x 16) + place slice (epb edges) ----
// LDS = 32KB only (sW1, reused as sT) -> 4 blocks/CU. GEMM2 B direct from Wt2t (L1/L2).
__global__ __launch_bounds__(512, 4) void k_mlp_place(
        const float* __restrict__ feat,
        const unsigned short* __restrict__ Wt1s,
        const unsigned short* __restrict__ Wt2t,
        const float* __restrict__ b1, const float* __restrict__ b2,
        unsigned short* __restrict__ hbf, int n,
        const int* __restrict__ src, const int* __restrict__ dst,
        const float* __restrict__ W_edge,
        unsigned int* __restrict__ packed,
        int* __restrict__ ovf_cnt, int4* __restrict__ ovf,
        float2* __restrict__ pairs, int E, int epb) {
    __shared__ unsigned short sW1[128 * D];  // swizzled Wt1; later sT (32 KB total LDS)
    const int t = threadIdx.x;
    const int lane = t & 63;
    const int w = t >> 6;                      // wave 0..7
    const int rl0 = w * 16;                    // wave's rows in sT
    const int row0 = blockIdx.x * 128 + rl0;   // wave's global rows
    const int rA = lane & 15;
    const int ks = (lane >> 4) * 8;

    // 0) issue this block's edge-slice loads (coalesced; 2 edges/thread max)
    const int ebase = blockIdx.x * epb;
    const int e1 = ebase + t;
    const int e2 = e1 + 512;
    const bool v1 = (t < epb) && (e1 < E);
    const bool v2 = (t < epb - 512) && (e2 < E);
    int s1 = 0, d1 = 0, s2 = 0, d2 = 0;
    float ew1 = 0.f, ew2 = 0.f;
    if (v1) { s1 = src[e1]; d1 = dst[e1]; ew1 = W_edge[e1]; }
    if (v2) { s2 = src[e2]; d2 = dst[e2]; ew2 = W_edge[e2]; }

    // 1) issue feat loads (HBM latency hides under W staging)
    float4 f[4][2];
    {
        int gr = row0 + rA;
        bool ok = gr < n;
        const float* fp = &feat[(size_t)(ok ? gr : 0) * D + ks];
#pragma unroll
        for (int kc = 0; kc < 4; ++kc) {
            f[kc][0] = ok ? *(const float4*)(fp + kc * 32) : make_float4(0.f, 0.f, 0.f, 0.f);
            f[kc][1] = ok ? *(const float4*)(fp + kc * 32 + 4) : make_float4(0.f, 0.f, 0.f, 0.f);
        }
    }

    // 2) stage swizzled W1 image linearly into LDS (512 thr x 4 x 16B)
    {
        const ushort8_s* g1 = (const ushort8_s*)Wt1s;
        ushort8_s* l1 = (ushort8_s*)sW1;
#pragma unroll
        for (int j = 0; j < 4; ++j) {
            int c = t + j * 512;
            l1[c] = g1[c];
        }
    }

    // 3) issue the bucket atomics now — latency drains with the staging barrier
    unsigned int old1 = 0, old2 = 0;
    if (v1) old1 = atomicAdd(&packed[s1], (s1 == d1) ? 0x10001u : 1u);
    if (v2) old2 = atomicAdd(&packed[s2], (s2 == d2) ? 0x10001u : 1u);

    float bias1[8], bias2[8];
#pragma unroll
    for (int nf = 0; nf < 8; ++nf) {
        bias1[nf] = b1[nf * 16 + rA];
        bias2[nf] = b2[nf * 16 + rA];
    }

    short8 afrag[4];
#pragma unroll
    for (int kc = 0; kc < 4; ++kc) {
        float4 f0 = f[kc][0], f1 = f[kc][1];
        short8 a;
        a[0] = (short)f2bf(f0.x); a[1] = (short)f2bf(f0.y);
        a[2] = (short)f2bf(f0.z); a[3] = (short)f2bf(f0.w);
        a[4] = (short)f2bf(f1.x); a[5] = (short)f2bf(f1.y);
        a[6] = (short)f2bf(f1.z); a[7] = (short)f2bf(f1.w);
        afrag[kc] = a;
    }

    __syncthreads();  // W1 staged (also drains edge loads + atomics)

    f32x4 acc[8];
#pragma unroll
    for (int nf = 0; nf < 8; ++nf) acc[nf] = (f32x4){0.f, 0.f, 0.f, 0.f};

    // GEMM1: B from sW1 (LDS)
#pragma unroll
    for (int kc = 0; kc < 4; ++kc) {
        const int kb = (kc * 32 + ks) * 2;
#pragma unroll
        for (int nf = 0; nf < 8; ++nf) {
            const int rb = nf * 16 + rA;
            short8 b = *(short8*)((char*)sW1 + swz(rb, kb));
            acc[nf] = __builtin_amdgcn_mfma_f32_16x16x32_bf16(afrag[kc], b, acc[nf], 0, 0, 0);
        }
    }

    __syncthreads();  // all B-reads of sW1 done before it becomes sT

    // tanh -> own 16 rows of sT (= sW1 space); wave-local from here on
#pragma unroll
    for (int nf = 0; nf < 8; ++nf) {
        const int col = nf * 16 + rA;
#pragma unroll
        for (int i = 0; i < 4; ++i) {
            const int rl = rl0 + (lane >> 4) * 4 + i;
            unsigned short hv = f2bf(fast_tanh(acc[nf][i] + bias1[nf]));
            *(unsigned short*)((char*)sW1 + swz(rl, col * 2)) = hv;
        }
    }

#pragma unroll
    for (int nf = 0; nf < 8; ++nf) acc[nf] = (f32x4){0.f, 0.f, 0.f, 0.f};

    // GEMM2: A from own sT rows (LDS), B direct from Wt2t (L1/L2-resident 32KB)
#pragma unroll
    for (int kc = 0; kc < 4; ++kc) {
        const int kb = (kc * 32 + ks) * 2;
        const int ra0 = rl0 + rA;
        short8 a0 = *(short8*)((char*)sW1 + swz(ra0, kb));
#pragma unroll
        for (int nf = 0; nf < 8; ++nf) {
            short8 b = *(const short8*)&Wt2t[(nf * 16 + rA) * D + kc * 32 + ks];
            acc[nf] = __builtin_amdgcn_mfma_f32_16x16x32_bf16(a0, b, acc[nf], 0, 0, 0);
        }
    }

    // epilogue: +b2 -> bf16 -> own sT rows
#pragma unroll
    for (int nf = 0; nf < 8; ++nf) {
        const int col = nf * 16 + rA;
#pragma unroll
        for (int i = 0; i < 4; ++i) {
            const int rl = rl0 + (lane >> 4) * 4 + i;
            unsigned short hv = f2bf(acc[nf][i] + bias2[nf]);
            *(unsigned short*)((char*)sW1 + swz(rl, col * 2)) = hv;
        }
    }

    // coalesced store of own 16 rows
    for (int c = lane; c < 256; c += 64) {
        int r = c >> 4, k0 = (c & 15) * 8;
        int gr = row0 + r;
        if (gr < n) {
            int rl = rl0 + r;
            short8 v = *(short8*)((char*)sW1 + swz(rl, k0 * 2));
            *(short8*)&hbf[(size_t)gr * D + k0] = v;
        }
    }

    // 4) place stores (ranks already secured; fire-and-forget)
    if (v1) {
        int rank = (int)(old1 & 0xffffu);
        if (rank < MAXDEG) {
            float2 p;
            p.x = __int_as_float(d1);
            p.y = ew1;
            pairs[(size_t)s1 * MAXDEG + rank] = p;
        } else {
            int oi = atomicAdd(ovf_cnt, 1);
            if (oi < OVF_CAP) ovf[oi] = make_int4(s1, d1, __float_as_int(ew1), 0);
        }
    }
    if (v2) {
        int rank = (int)(old2 & 0xffffu);
        if (rank < MAXDEG) {
            float2 p;
            p.x = __int_as_float(d2);
            p.y = ew2;
            pairs[(size_t)s2 * MAXDEG + rank] = p;
        } else {
            int oi = atomicAdd(ovf_cnt, 1);
            if (oi < OVF_CAP) ovf[oi] = make_int4(s2, d2, __float_as_int(ew2), 0);
        }
    }
}

// ---- K2: aggregate (r12 style), 16 lanes/node; degree from packed; 4-deep unroll ----
__global__ __launch_bounds__(256) void k_aggregate(const unsigned int* __restrict__ packed,
                                                   const float2* __restrict__ pairs,
                                                   const int* __restrict__ ovf_cnt,
                                                   const int4* __restrict__ ovf,
                                                   const unsigned short* __restrict__ hbf,
                                                   const int* __restrict__ indp,
                                                   float* __restrict__ out, int n) {
    long long tid = (long long)blockIdx.x * 256 + threadIdx.x;
    int node = (int)(tid >> 4);
    int li = (int)(tid & 15);
    int lane = threadIdx.x & 63;
    if (node >= n) return;
    const float maskm1 = ((indp[0] < 2) ? 1.0f : 0.0f) - 1.0f;  // MASK=(1,1,0,0)

    int cnt = (int)(packed[node] & 0xffffu);
    int mt = (cnt < MAXDEG) ? cnt : MAXDEG;

    float acc[8];
#pragma unroll
    for (int j = 0; j < 8; ++j) acc[j] = 0.f;
    float rsp = 0.f;
    const int gbase = lane & 48;
    const float2* prow = &pairs[(size_t)node * MAXDEG];

    auto fma8 = [&](float w, uint4 h) {
        acc[0] = fmaf(w, bflo(h.x), acc[0]); acc[1] = fmaf(w, bfhi(h.x), acc[1]);
        acc[2] = fmaf(w, bflo(h.y), acc[2]); acc[3] = fmaf(w, bfhi(h.y), acc[3]);
        acc[4] = fmaf(w, bflo(h.z), acc[4]); acc[5] = fmaf(w, bfhi(h.z), acc[5]);
        acc[6] = fmaf(w, bflo(h.w), acc[6]); acc[7] = fmaf(w, bfhi(h.w), acc[7]);
    };

    for (int base = 0; base < mt; base += 16) {
        int mm = mt - base;
        mm = (mm > 16) ? 16 : mm;
        float wv = 0.f;
        float dv = 0.f;
        if (li < mm) {
            float2 p = prow[base + li];
            dv = p.x;
            int d = __float_as_int(p.x);
            unsigned int pkd = packed[d];
            float deg = (float)(pkd & 0xffffu) + maskm1 * (float)(pkd >> 16);
            wv = deg * p.y;
        }
        rsp += wv;
        int i = 0;
        for (; i + 3 < mm; i += 4) {
            int d0 = __float_as_int(__shfl(dv, gbase + i));
            float w0 = __shfl(wv, gbase + i);
            int d1 = __float_as_int(__shfl(dv, gbase + i + 1));
            float w1 = __shfl(wv, gbase + i + 1);
            int d2 = __float_as_int(__shfl(dv, gbase + i + 2));
            float w2 = __shfl(wv, gbase + i + 2);
            int d3 = __float_as_int(__shfl(dv, gbase + i + 3));
            float w3 = __shfl(wv, gbase + i + 3);
            uint4 h0 = *(const uint4*)&hbf[(size_t)d0 * D + li * 8];
            uint4 h1 = *(const uint4*)&hbf[(size_t)d1 * D + li * 8];
            uint4 h2 = *(const uint4*)&hbf[(size_t)d2 * D + li * 8];
            uint4 h3 = *(const uint4*)&hbf[(size_t)d3 * D + li * 8];
            fma8(w0, h0); fma8(w1, h1); fma8(w2, h2); fma8(w3, h3);
        }
        for (; i + 1 < mm; i += 2) {
            int d0 = __float_as_int(__shfl(dv, gbase + i));
            float w0 = __shfl(wv, gbase + i);
            int d1 = __float_as_int(__shfl(dv, gbase + i + 1));
            float w1 = __shfl(wv, gbase + i + 1);
            uint4 h0 = *(const uint4*)&hbf[(size_t)d0 * D + li * 8];
            uint4 h1 = *(const uint4*)&hbf[(size_t)d1 * D + li * 8];
            fma8(w0, h0); fma8(w1, h1);
        }
        if (i < mm) {
            int d0 = __float_as_int(__shfl(dv, gbase + i));
            float w0 = __shfl(wv, gbase + i);
            uint4 h0 = *(const uint4*)&hbf[(size_t)d0 * D + li * 8];
            fma8(w0, h0);
        }
    }

    // overflow pass (normally empty; exactness fallback)
    int ovn = *ovf_cnt;
    if (ovn > OVF_CAP) ovn = OVF_CAP;
    for (int i = 0; i < ovn; ++i) {
        int4 tq = ovf[i];
        if (tq.x == node) {
            int d = tq.y;
            unsigned int pkd = packed[d];
            float deg = (float)(pkd & 0xffffu) + maskm1 * (float)(pkd >> 16);
            float w = deg * __int_as_float(tq.z);
            if (li == 0) rsp += w;
            uint4 h = *(const uint4*)&hbf[(size_t)d * D + li * 8];
            fma8(w, h);
        }
    }

    rsp += __shfl_xor(rsp, 1);
    rsp += __shfl_xor(rsp, 2);
    rsp += __shfl_xor(rsp, 4);
    rsp += __shfl_xor(rsp, 8);
    rsp = (rsp == 0.f) ? 1.f : rsp;
    float inv = 1.0f / rsp;
    float4 o0, o1;
    o0.x = acc[0] * inv; o0.y = acc[1] * inv; o0.z = acc[2] * inv; o0.w = acc[3] * inv;
    o1.x = acc[4] * inv; o1.y = acc[5] * inv; o1.z = acc[6] * inv; o1.w = acc[7] * inv;
    float* op = &out[(size_t)node * D + li * 8];
    *(float4*)op = o0;
    *(float4*)(op + 4) = o1;
}

extern "C" void kernel_launch(void* const* d_in, const int* in_sizes, int n_in,
                              void* d_out, int out_size, void* d_ws, size_t ws_size,
                              hipStream_t stream) {
    const float* feat   = (const float*)d_in[0];
    const float* W_edge = (const float*)d_in[1];
    const float* W1     = (const float*)d_in[2];
    const float* b1     = (const float*)d_in[3];
    const float* W2     = (const float*)d_in[4];
    const float* b2     = (const float*)d_in[5];
    const int* edge_src = (const int*)d_in[6];
    const int* edge_dst = (const int*)d_in[7];
    const int* indp     = (const int*)d_in[8];

    const int n = in_sizes[0] / D;   // 100000
    const int E = in_sizes[6];       // 600000

    // ws (16B-aligned): Wt1s u16[D*D] | Wt2t u16[D*D] | packed u32[n] | ovf_cnt i32 +pad |
    //                   ovf int4[OVF_CAP] | pairs f2[n*MAXDEG] | hbf u16[n*D]
    char* ws = (char*)d_ws;
    unsigned short* Wt1s = (unsigned short*)ws;
    unsigned short* Wt2t = Wt1s + D * D;
    unsigned int* packed = (unsigned int*)(Wt2t + D * D);
    int* ovf_cnt         = (int*)(packed + n);
    int4* ovf            = (int4*)((char*)ovf_cnt + 16);
    float2* pairs        = (float2*)(ovf + OVF_CAP);
    unsigned short* hbf  = (unsigned short*)(pairs + (size_t)n * MAXDEG);

    // K0: prep W (64 blocks) + zero packed..ovf_cnt (rest)
    const int zbytes = n * 4 + 16;           // packed + ovf_cnt(+pad)
    const int zv4 = zbytes / 16;
    const int zb = (zv4 + 255) / 256;
    k_init<<<64 + zb, 256, 0, stream>>>(W1, W2, Wt1s, Wt2t, (int*)packed, zv4);

    // K1: merged mlp+place — every block does 128 rows AND epb edges; 32KB LDS
    const int nm = (n + 127) / 128;          // 782
    const int epb = (E + nm - 1) / nm;       // 768
    k_mlp_place<<<nm, 512, 0, stream>>>(feat, Wt1s, Wt2t, b1, b2, hbf, n,
                                        edge_src, edge_dst, W_edge,
                                        packed, ovf_cnt, ovf, pairs, E, epb);

    // K2: aggregate (per-node groups, max TLP)
    long long athreads = (long long)n * 16;
    k_aggregate<<<(int)((athreads + 255) / 256), 256, 0, stream>>>(packed, pairs, ovf_cnt,
                                                                   ovf, hbf, indp,
                                                                   (float*)d_out, n);
}

// Round 19
// 94.473 us; speedup vs baseline: 1.2088x; 1.2088x over previous
//
#include <hip/hip_runtime.h>

// MeanAggregator on MI355X — best-of recombination.
// k_init -> k_mlp_place (merged MLP+place, 64KB LDS, plain stores) -> k_aggregate (per-node, 4-deep).

constexpr int D = 128;
constexpr int MAXDEG = 24;
constexpr int OVF_CAP = 131072;

typedef __attribute__((ext_vector_type(8))) short short8;
typedef __attribute__((ext_vector_type(4))) float f32x4;
struct ushort8_s { unsigned short v[8]; };

__device__ __forceinline__ unsigned short f2bf(float x) {
    unsigned int u = __float_as_uint(x);
    u += 0x7fffu + ((u >> 16) & 1u);
    return (unsigned short)(u >> 16);
}
__device__ __forceinline__ float bflo(unsigned int u) { return __uint_as_float(u << 16); }
__device__ __forceinline__ float bfhi(unsigned int u) { return __uint_as_float(u & 0xffff0000u); }
__device__ __forceinline__ float fast_tanh(float x) {
    float e = exp2f(x * 2.885390081777927f);
    return fmaf(-2.0f, __builtin_amdgcn_rcpf(e + 1.0f), 1.0f);
}
// swizzled byte offset inside a [128 rows x 256 B] tile
__device__ __forceinline__ int swz(int row, int kbyte) {
    return (row * 256 + kbyte) ^ ((row & 7) << 4);
}

// ---- K0: W transpose->bf16 PRE-SWIZZLED (blocks 0..63) | zero packed+ovf_cnt (rest) ----
__global__ __launch_bounds__(256) void k_init(const float* __restrict__ W1,
                                              const float* __restrict__ W2,
                                              unsigned short* __restrict__ Wt1s,
                                              unsigned short* __restrict__ Wt2s,
                                              int* __restrict__ zbase, int zv4) {
    int b = blockIdx.x;
    if (b < 64) {
        int t = b * 256 + threadIdx.x;  // t = k*D + nn (coalesced read)
        int k = t >> 7, nn = t & 127;
        int si = swz(nn, k * 2) >> 1;   // u16 index in swizzled image
        Wt1s[si] = f2bf(W1[t]);
        Wt2s[si] = f2bf(W2[t]);
    } else {
        int i = (b - 64) * 256 + threadIdx.x;
        if (i < zv4) ((int4*)zbase)[i] = make_int4(0, 0, 0, 0);
    }
}

// ---- K1: every block = MLP (128 rows, 8 waves x 16) + place slice (epb edges) ----
__global__ __launch_bounds__(512, 4) void k_mlp_place(
        const float* __restrict__ feat,
        const unsigned short* __restrict__ Wt1s,
        const unsigned short* __restrict__ Wt2s,
        const float* __restrict__ b1, const float* __restrict__ b2,
        unsigned short* __restrict__ hbf, int n,
        const int* __restrict__ src, const int* __restrict__ dst,
        const float* __restrict__ W_edge,
        unsigned int* __restrict__ packed,
        int* __restrict__ ovf_cnt, int4* __restrict__ ovf,
        float2* __restrict__ pairs, int E, int epb) {
    __shared__ unsigned short sW1[128 * D];  // swizzled Wt1; later sT
    __shared__ unsigned short sW2[128 * D];  // swizzled Wt2
    const int t = threadIdx.x;
    const int lane = t & 63;
    const int w = t >> 6;                      // wave 0..7
    const int rl0 = w * 16;                    // wave's rows in sT
    const int row0 = blockIdx.x * 128 + rl0;   // wave's global rows
    const int rA = lane & 15;
    const int ks = (lane >> 4) * 8;

    // 0) issue this block's edge-slice loads (coalesced; 2 edges/thread max)
    const int ebase = blockIdx.x * epb;
    const int e1 = ebase + t;
    const int e2 = e1 + 512;
    const bool v1 = (t < epb) && (e1 < E);
    const bool v2 = (t < epb - 512) && (e2 < E);
    int s1 = 0, d1 = 0, s2 = 0, d2 = 0;
    float ew1 = 0.f, ew2 = 0.f;
    if (v1) { s1 = src[e1]; d1 = dst[e1]; ew1 = W_edge[e1]; }
    if (v2) { s2 = src[e2]; d2 = dst[e2]; ew2 = W_edge[e2]; }

    // 1) issue feat loads (HBM latency hides under W staging)
    float4 f[4][2];
    {
        int gr = row0 + rA;
        bool ok = gr < n;
        const float* fp = &feat[(size_t)(ok ? gr : 0) * D + ks];
#pragma unroll
        for (int kc = 0; kc < 4; ++kc) {
            f[kc][0] = ok ? *(const float4*)(fp + kc * 32) : make_float4(0.f, 0.f, 0.f, 0.f);
            f[kc][1] = ok ? *(const float4*)(fp + kc * 32 + 4) : make_float4(0.f, 0.f, 0.f, 0.f);
        }
    }

    // 2) stage swizzled W images linearly into LDS
    {
        const ushort8_s* g1 = (const ushort8_s*)Wt1s;
        const ushort8_s* g2 = (const ushort8_s*)Wt2s;
        ushort8_s* l1 = (ushort8_s*)sW1;
        ushort8_s* l2 = (ushort8_s*)sW2;
#pragma unroll
        for (int j = 0; j < 4; ++j) {
            int c = t + j * 512;
            l1[c] = g1[c];
            l2[c] = g2[c];
        }
    }

    // 3) issue the bucket atomics now — latency drains with the staging barrier
    unsigned int old1 = 0, old2 = 0;
    if (v1) old1 = atomicAdd(&packed[s1], (s1 == d1) ? 0x10001u : 1u);
    if (v2) old2 = atomicAdd(&packed[s2], (s2 == d2) ? 0x10001u : 1u);

    float bias1[8], bias2[8];
#pragma unroll
    for (int nf = 0; nf < 8; ++nf) {
        bias1[nf] = b1[nf * 16 + rA];
        bias2[nf] = b2[nf * 16 + rA];
    }

    short8 afrag[4];
#pragma unroll
    for (int kc = 0; kc < 4; ++kc) {
        float4 f0 = f[kc][0], f1 = f[kc][1];
        short8 a;
        a[0] = (short)f2bf(f0.x); a[1] = (short)f2bf(f0.y);
        a[2] = (short)f2bf(f0.z); a[3] = (short)f2bf(f0.w);
        a[4] = (short)f2bf(f1.x); a[5] = (short)f2bf(f1.y);
        a[6] = (short)f2bf(f1.z); a[7] = (short)f2bf(f1.w);
        afrag[kc] = a;
    }

    __syncthreads();  // W staged (also drains edge loads + atomics)

    f32x4 acc[8];
#pragma unroll
    for (int nf = 0; nf < 8; ++nf) acc[nf] = (f32x4){0.f, 0.f, 0.f, 0.f};

    // GEMM1: B from sW1
#pragma unroll
    for (int kc = 0; kc < 4; ++kc) {
        const int kb = (kc * 32 + ks) * 2;
#pragma unroll
        for (int nf = 0; nf < 8; ++nf) {
            const int rb = nf * 16 + rA;
            short8 b = *(short8*)((char*)sW1 + swz(rb, kb));
            acc[nf] = __builtin_amdgcn_mfma_f32_16x16x32_bf16(afrag[kc], b, acc[nf], 0, 0, 0);
        }
    }

    __syncthreads();  // all B-reads of sW1 done before it becomes sT

    // tanh -> own 16 rows of sT (= sW1 space); wave-local from here on
#pragma unroll
    for (int nf = 0; nf < 8; ++nf) {
        const int col = nf * 16 + rA;
#pragma unroll
        for (int i = 0; i < 4; ++i) {
            const int rl = rl0 + (lane >> 4) * 4 + i;
            unsigned short hv = f2bf(fast_tanh(acc[nf][i] + bias1[nf]));
            *(unsigned short*)((char*)sW1 + swz(rl, col * 2)) = hv;
        }
    }

#pragma unroll
    for (int nf = 0; nf < 8; ++nf) acc[nf] = (f32x4){0.f, 0.f, 0.f, 0.f};

    // GEMM2: A from own sT rows, B from sW2
#pragma unroll
    for (int kc = 0; kc < 4; ++kc) {
        const int kb = (kc * 32 + ks) * 2;
        const int ra0 = rl0 + rA;
        short8 a0 = *(short8*)((char*)sW1 + swz(ra0, kb));
#pragma unroll
        for (int nf = 0; nf < 8; ++nf) {
            const int rb = nf * 16 + rA;
            short8 b = *(short8*)((char*)sW2 + swz(rb, kb));
            acc[nf] = __builtin_amdgcn_mfma_f32_16x16x32_bf16(a0, b, acc[nf], 0, 0, 0);
        }
    }

    // epilogue: +b2 -> bf16 -> own sT rows
#pragma unroll
    for (int nf = 0; nf < 8; ++nf) {
        const int col = nf * 16 + rA;
#pragma unroll
        for (int i = 0; i < 4; ++i) {
            const int rl = rl0 + (lane >> 4) * 4 + i;
            unsigned short hv = f2bf(acc[nf][i] + bias2[nf]);
            *(unsigned short*)((char*)sW1 + swz(rl, col * 2)) = hv;
        }
    }

    // coalesced store of own 16 rows
    for (int c = lane; c < 256; c += 64) {
        int r = c >> 4, k0 = (c & 15) * 8;
        int gr = row0 + r;
        if (gr < n) {
            int rl = rl0 + r;
            short8 v = *(short8*)((char*)sW1 + swz(rl, k0 * 2));
            *(short8*)&hbf[(size_t)gr * D + k0] = v;
        }
    }

    // 4) place stores (ranks already secured; fire-and-forget, plain stores)
    if (v1) {
        int rank = (int)(old1 & 0xffffu);
        if (rank < MAXDEG) {
            float2 p;
            p.x = __int_as_float(d1);
            p.y = ew1;
            pairs[(size_t)s1 * MAXDEG + rank] = p;
        } else {
            int oi = atomicAdd(ovf_cnt, 1);
            if (oi < OVF_CAP) ovf[oi] = make_int4(s1, d1, __float_as_int(ew1), 0);
        }
    }
    if (v2) {
        int rank = (int)(old2 & 0xffffu);
        if (rank < MAXDEG) {
            float2 p;
            p.x = __int_as_float(d2);
            p.y = ew2;
            pairs[(size_t)s2 * MAXDEG + rank] = p;
        } else {
            int oi = atomicAdd(ovf_cnt, 1);
            if (oi < OVF_CAP) ovf[oi] = make_int4(s2, d2, __float_as_int(ew2), 0);
        }
    }
}

// ---- K2: aggregate, per-node groups (max TLP), 16 lanes/node, 4-deep unroll ----
__global__ __launch_bounds__(256) void k_aggregate(const unsigned int* __restrict__ packed,
                                                   const float2* __restrict__ pairs,
                                                   const int* __restrict__ ovf_cnt,
                                                   const int4* __restrict__ ovf,
                                                   const unsigned short* __restrict__ hbf,
                                                   const int* __restrict__ indp,
                                                   float* __restrict__ out, int n) {
    long long tid = (long long)blockIdx.x * 256 + threadIdx.x;
    int node = (int)(tid >> 4);
    int li = (int)(tid & 15);
    int lane = threadIdx.x & 63;
    if (node >= n) return;
    const float maskm1 = ((indp[0] < 2) ? 1.0f : 0.0f) - 1.0f;  // MASK=(1,1,0,0)

    int cnt = (int)(packed[node] & 0xffffu);
    int mt = (cnt < MAXDEG) ? cnt : MAXDEG;

    float acc[8];
#pragma unroll
    for (int j = 0; j < 8; ++j) acc[j] = 0.f;
    float rsp = 0.f;
    const int gbase = lane & 48;
    const float2* prow = &pairs[(size_t)node * MAXDEG];

    auto fma8 = [&](float w, uint4 h) {
        acc[0] = fmaf(w, bflo(h.x), acc[0]); acc[1] = fmaf(w, bfhi(h.x), acc[1]);
        acc[2] = fmaf(w, bflo(h.y), acc[2]); acc[3] = fmaf(w, bfhi(h.y), acc[3]);
        acc[4] = fmaf(w, bflo(h.z), acc[4]); acc[5] = fmaf(w, bfhi(h.z), acc[5]);
        acc[6] = fmaf(w, bflo(h.w), acc[6]); acc[7] = fmaf(w, bfhi(h.w), acc[7]);
    };

    for (int base = 0; base < mt; base += 16) {
        int mm = mt - base;
        mm = (mm > 16) ? 16 : mm;
        float wv = 0.f;
        float dv = 0.f;
        if (li < mm) {
            float2 p = prow[base + li];
            dv = p.x;
            int d = __float_as_int(p.x);
            unsigned int pkd = packed[d];
            float deg = (float)(pkd & 0xffffu) + maskm1 * (float)(pkd >> 16);
            wv = deg * p.y;
        }
        rsp += wv;
        int i = 0;
        for (; i + 3 < mm; i += 4) {
            int d0 = __float_as_int(__shfl(dv, gbase + i));
            float w0 = __shfl(wv, gbase + i);
            int d1 = __float_as_int(__shfl(dv, gbase + i + 1));
            float w1 = __shfl(wv, gbase + i + 1);
            int d2 = __float_as_int(__shfl(dv, gbase + i + 2));
            float w2 = __shfl(wv, gbase + i + 2);
            int d3 = __float_as_int(__shfl(dv, gbase + i + 3));
            float w3 = __shfl(wv, gbase + i + 3);
            uint4 h0 = *(const uint4*)&hbf[(size_t)d0 * D + li * 8];
            uint4 h1 = *(const uint4*)&hbf[(size_t)d1 * D + li * 8];
            uint4 h2 = *(const uint4*)&hbf[(size_t)d2 * D + li * 8];
            uint4 h3 = *(const uint4*)&hbf[(size_t)d3 * D + li * 8];
            fma8(w0, h0); fma8(w1, h1); fma8(w2, h2); fma8(w3, h3);
        }
        for (; i + 1 < mm; i += 2) {
            int d0 = __float_as_int(__shfl(dv, gbase + i));
            float w0 = __shfl(wv, gbase + i);
            int d1 = __float_as_int(__shfl(dv, gbase + i + 1));
            float w1 = __shfl(wv, gbase + i + 1);
            uint4 h0 = *(const uint4*)&hbf[(size_t)d0 * D + li * 8];
            uint4 h1 = *(const uint4*)&hbf[(size_t)d1 * D + li * 8];
            fma8(w0, h0); fma8(w1, h1);
        }
        if (i < mm) {
            int d0 = __float_as_int(__shfl(dv, gbase + i));
            float w0 = __shfl(wv, gbase + i);
            uint4 h0 = *(const uint4*)&hbf[(size_t)d0 * D + li * 8];
            fma8(w0, h0);
        }
    }

    // overflow pass (normally empty; exactness fallback)
    int ovn = *ovf_cnt;
    if (ovn > OVF_CAP) ovn = OVF_CAP;
    for (int i = 0; i < ovn; ++i) {
        int4 tq = ovf[i];
        if (tq.x == node) {
            int d = tq.y;
            unsigned int pkd = packed[d];
            float deg = (float)(pkd & 0xffffu) + maskm1 * (float)(pkd >> 16);
            float w = deg * __int_as_float(tq.z);
            if (li == 0) rsp += w;
            uint4 h = *(const uint4*)&hbf[(size_t)d * D + li * 8];
            fma8(w, h);
        }
    }

    rsp += __shfl_xor(rsp, 1);
    rsp += __shfl_xor(rsp, 2);
    rsp += __shfl_xor(rsp, 4);
    rsp += __shfl_xor(rsp, 8);
    rsp = (rsp == 0.f) ? 1.f : rsp;
    float inv = 1.0f / rsp;
    float4 o0, o1;
    o0.x = acc[0] * inv; o0.y = acc[1] * inv; o0.z = acc[2] * inv; o0.w = acc[3] * inv;
    o1.x = acc[4] * inv; o1.y = acc[5] * inv; o1.z = acc[6] * inv; o1.w = acc[7] * inv;
    float* op = &out[(size_t)node * D + li * 8];
    *(float4*)op = o0;
    *(float4*)(op + 4) = o1;
}

extern "C" void kernel_launch(void* const* d_in, const int* in_sizes, int n_in,
                              void* d_out, int out_size, void* d_ws, size_t ws_size,
                              hipStream_t stream) {
    const float* feat   = (const float*)d_in[0];
    const float* W_edge = (const float*)d_in[1];
    const float* W1     = (const float*)d_in[2];
    const float* b1     = (const float*)d_in[3];
    const float* W2     = (const float*)d_in[4];
    const float* b2     = (const float*)d_in[5];
    const int* edge_src = (const int*)d_in[6];
    const int* edge_dst = (const int*)d_in[7];
    const int* indp     = (const int*)d_in[8];

    const int n = in_sizes[0] / D;   // 100000
    const int E = in_sizes[6];       // 600000

    // ws (16B-aligned): Wt1s u16[D*D] | Wt2s u16[D*D] | packed u32[n] | ovf_cnt i32 +pad |
    //                   ovf int4[OVF_CAP] | pairs f2[n*MAXDEG] | hbf u16[n*D]
    char* ws = (char*)d_ws;
    unsigned short* Wt1s = (unsigned short*)ws;
    unsigned short* Wt2s = Wt1s + D * D;
    unsigned int* packed = (unsigned int*)(Wt2s + D * D);
    int* ovf_cnt         = (int*)(packed + n);
    int4* ovf            = (int4*)((char*)ovf_cnt + 16);
    float2* pairs        = (float2*)(ovf + OVF_CAP);
    unsigned short* hbf  = (unsigned short*)(pairs + (size_t)n * MAXDEG);

    // K0: prep W (64 blocks) + zero packed..ovf_cnt (rest)
    const int zbytes = n * 4 + 16;           // packed + ovf_cnt(+pad)
    const int zv4 = zbytes / 16;
    const int zb = (zv4 + 255) / 256;
    k_init<<<64 + zb, 256, 0, stream>>>(W1, W2, Wt1s, Wt2s, (int*)packed, zv4);

    // K1: merged mlp+place — every block does 128 rows AND epb edges
    const int nm = (n + 127) / 128;          // 782
    const int epb = (E + nm - 1) / nm;       // 768
    k_mlp_place<<<nm, 512, 0, stream>>>(feat, Wt1s, Wt2s, b1, b2, hbf, n,
                                        edge_src, edge_dst, W_edge,
                                        packed, ovf_cnt, ovf, pairs, E, epb);

    // K2: aggregate (per-node groups, max TLP)
    long long athreads = (long long)n * 16;
    k_aggregate<<<(int)((athreads + 255) / 256), 256, 0, stream>>>(packed, pairs, ovf_cnt,
                                                                   ovf, hbf, indp,
                                                                   (float*)d_out, n);
}

// Round 20
// 90.790 us; speedup vs baseline: 1.2578x; 1.0406x over previous
//
#include <hip/hip_runtime.h>

// MeanAggregator on MI355X — measured-best configuration (r12).
// k_init (Wprep + zero) -> k_mlp_place (interleaved roles) -> k_aggregate.
// CSR replaced by fixed-stride buckets (MAXDEG=24) + exact overflow list.

constexpr int D = 128;
constexpr int MAXDEG = 24;
constexpr int OVF_CAP = 131072;

typedef __attribute__((ext_vector_type(8))) short short8;
typedef __attribute__((ext_vector_type(4))) float f32x4;
struct ushort8_s { unsigned short v[8]; };

__device__ __forceinline__ unsigned short f2bf(float x) {
    unsigned int u = __float_as_uint(x);
    u += 0x7fffu + ((u >> 16) & 1u);
    return (unsigned short)(u >> 16);
}
__device__ __forceinline__ float bflo(unsigned int u) { return __uint_as_float(u << 16); }
__device__ __forceinline__ float bfhi(unsigned int u) { return __uint_as_float(u & 0xffff0000u); }
__device__ __forceinline__ float fast_tanh(float x) {
    float e = exp2f(x * 2.885390081777927f);
    return fmaf(-2.0f, __builtin_amdgcn_rcpf(e + 1.0f), 1.0f);
}
// swizzled byte offset inside a [128 rows x 256 B] tile
__device__ __forceinline__ int swz(int row, int kbyte) {
    return (row * 256 + kbyte) ^ ((row & 7) << 4);
}

// ---- K0: W transpose->bf16 PRE-SWIZZLED (blocks 0..63) | zero packed+ovf_cnt (rest) ----
__global__ __launch_bounds__(256) void k_init(const float* __restrict__ W1,
                                              const float* __restrict__ W2,
                                              unsigned short* __restrict__ Wt1s,
                                              unsigned short* __restrict__ Wt2s,
                                              int* __restrict__ zbase, int zv4) {
    int b = blockIdx.x;
    if (b < 64) {
        int t = b * 256 + threadIdx.x;  // t = k*D + nn (coalesced read)
        int k = t >> 7, nn = t & 127;
        int si = swz(nn, k * 2) >> 1;   // u16 index in swizzled image
        Wt1s[si] = f2bf(W1[t]);
        Wt2s[si] = f2bf(W2[t]);
    } else {
        int i = (b - 64) * 256 + threadIdx.x;
        if (i < zv4) ((int4*)zbase)[i] = make_int4(0, 0, 0, 0);
    }
}

// ---- K1: fused MLP | place (bucket scatter), block roles interleaved ----
// MLP: 128 rows/block, 8 waves x 16 rows; W staged once in LDS (sW1 reused as sT).
__global__ __launch_bounds__(512, 4) void k_mlp_place(
        const float* __restrict__ feat,
        const unsigned short* __restrict__ Wt1s,
        const unsigned short* __restrict__ Wt2s,
        const float* __restrict__ b1, const float* __restrict__ b2,
        unsigned short* __restrict__ hbf, int n, int nm, int npl,
        const int* __restrict__ src, const int* __restrict__ dst,
        const float* __restrict__ W_edge,
        unsigned int* __restrict__ packed,
        int* __restrict__ ovf_cnt, int4* __restrict__ ovf,
        float2* __restrict__ pairs, int E) {
    __shared__ unsigned short sW1[128 * D];  // swizzled Wt1; later sT
    __shared__ unsigned short sW2[128 * D];  // swizzled Wt2

    // interleave roles so MLP and place blocks co-reside on every CU
    const int bid = blockIdx.x;
    bool isMlp;
    int idx;
    if (nm <= npl) {
        if (bid < 2 * nm) { isMlp = !(bid & 1); idx = bid >> 1; }
        else { isMlp = false; idx = nm + (bid - 2 * nm); }
    } else {
        if (bid < 2 * npl) { isMlp = (bid & 1); idx = bid >> 1; }
        else { isMlp = true; idx = npl + (bid - 2 * npl); }
    }

    if (!isMlp) {
        int e = idx * 512 + threadIdx.x;
        if (e < E) {
            int s = src[e];
            int d = dst[e];
            float W = W_edge[e];
            unsigned int add = (s == d) ? 0x10001u : 1u;  // selfc in hi16, cnt in lo16
            unsigned int old = atomicAdd(&packed[s], add);
            int rank = (int)(old & 0xffffu);
            if (rank < MAXDEG) {
                float2 p;
                p.x = __int_as_float(d);
                p.y = W;
                pairs[(size_t)s * MAXDEG + rank] = p;
            } else {
                int oi = atomicAdd(ovf_cnt, 1);
                if (oi < OVF_CAP) ovf[oi] = make_int4(s, d, __float_as_int(W), 0);
            }
        }
        return;
    }
    const int t = threadIdx.x;
    const int lane = t & 63;
    const int w = t >> 6;                      // wave 0..7
    const int rl0 = w * 16;                    // wave's rows in sT
    const int row0 = idx * 128 + rl0;          // wave's global rows
    const int rA = lane & 15;
    const int ks = (lane >> 4) * 8;

    // 1) issue feat loads first (HBM latency hides under W staging)
    float4 f[4][2];
    {
        int gr = row0 + rA;
        bool ok = gr < n;
        const float* fp = &feat[(size_t)(ok ? gr : 0) * D + ks];
#pragma unroll
        for (int kc = 0; kc < 4; ++kc) {
            f[kc][0] = ok ? *(const float4*)(fp + kc * 32) : make_float4(0.f, 0.f, 0.f, 0.f);
            f[kc][1] = ok ? *(const float4*)(fp + kc * 32 + 4) : make_float4(0.f, 0.f, 0.f, 0.f);
        }
    }

    // 2) stage swizzled W images linearly into LDS
    {
        const ushort8_s* g1 = (const ushort8_s*)Wt1s;
        const ushort8_s* g2 = (const ushort8_s*)Wt2s;
        ushort8_s* l1 = (ushort8_s*)sW1;
        ushort8_s* l2 = (ushort8_s*)sW2;
#pragma unroll
        for (int j = 0; j < 4; ++j) {
            int c = t + j * 512;
            l1[c] = g1[c];
            l2[c] = g2[c];
        }
    }

    float bias1[8], bias2[8];
#pragma unroll
    for (int nf = 0; nf < 8; ++nf) {
        bias1[nf] = b1[nf * 16 + rA];
        bias2[nf] = b2[nf * 16 + rA];
    }

    short8 afrag[4];
#pragma unroll
    for (int kc = 0; kc < 4; ++kc) {
        float4 f0 = f[kc][0], f1 = f[kc][1];
        short8 a;
        a[0] = (short)f2bf(f0.x); a[1] = (short)f2bf(f0.y);
        a[2] = (short)f2bf(f0.z); a[3] = (short)f2bf(f0.w);
        a[4] = (short)f2bf(f1.x); a[5] = (short)f2bf(f1.y);
        a[6] = (short)f2bf(f1.z); a[7] = (short)f2bf(f1.w);
        afrag[kc] = a;
    }

    __syncthreads();  // W staged

    f32x4 acc[8];
#pragma unroll
    for (int nf = 0; nf < 8; ++nf) acc[nf] = (f32x4){0.f, 0.f, 0.f, 0.f};

    // GEMM1: B from sW1
#pragma unroll
    for (int kc = 0; kc < 4; ++kc) {
        const int kb = (kc * 32 + ks) * 2;
#pragma unroll
        for (int nf = 0; nf < 8; ++nf) {
            const int rb = nf * 16 + rA;
            short8 b = *(short8*)((char*)sW1 + swz(rb, kb));
            acc[nf] = __builtin_amdgcn_mfma_f32_16x16x32_bf16(afrag[kc], b, acc[nf], 0, 0, 0);
        }
    }

    __syncthreads();  // all B-reads of sW1 done before it becomes sT

    // tanh -> own 16 rows of sT (= sW1 space); wave-local from here on
#pragma unroll
    for (int nf = 0; nf < 8; ++nf) {
        const int col = nf * 16 + rA;
#pragma unroll
        for (int i = 0; i < 4; ++i) {
            const int rl = rl0 + (lane >> 4) * 4 + i;
            unsigned short hv = f2bf(fast_tanh(acc[nf][i] + bias1[nf]));
            *(unsigned short*)((char*)sW1 + swz(rl, col * 2)) = hv;
        }
    }

#pragma unroll
    for (int nf = 0; nf < 8; ++nf) acc[nf] = (f32x4){0.f, 0.f, 0.f, 0.f};

    // GEMM2: A from own sT rows, B from sW2
#pragma unroll
    for (int kc = 0; kc < 4; ++kc) {
        const int kb = (kc * 32 + ks) * 2;
        const int ra0 = rl0 + rA;
        short8 a0 = *(short8*)((char*)sW1 + swz(ra0, kb));
#pragma unroll
        for (int nf = 0; nf < 8; ++nf) {
            const int rb = nf * 16 + rA;
            short8 b = *(short8*)((char*)sW2 + swz(rb, kb));
            acc[nf] = __builtin_amdgcn_mfma_f32_16x16x32_bf16(a0, b, acc[nf], 0, 0, 0);
        }
    }

    // epilogue: +b2 -> bf16 -> own sT rows
#pragma unroll
    for (int nf = 0; nf < 8; ++nf) {
        const int col = nf * 16 + rA;
#pragma unroll
        for (int i = 0; i < 4; ++i) {
            const int rl = rl0 + (lane >> 4) * 4 + i;
            unsigned short hv = f2bf(acc[nf][i] + bias2[nf]);
            *(unsigned short*)((char*)sW1 + swz(rl, col * 2)) = hv;
        }
    }

    // coalesced store of own 16 rows
    for (int c = lane; c < 256; c += 64) {
        int r = c >> 4, k0 = (c & 15) * 8;
        int gr = row0 + r;
        if (gr < n) {
            int rl = rl0 + r;
            short8 v = *(short8*)((char*)sW1 + swz(rl, k0 * 2));
            *(short8*)&hbf[(size_t)gr * D + k0] = v;
        }
    }
}

// ---- K2: aggregate, 16 lanes/node; degree reconstructed from packed table ----
__global__ __launch_bounds__(256) void k_aggregate(const unsigned int* __restrict__ packed,
                                                   const float2* __restrict__ pairs,
                                                   const int* __restrict__ ovf_cnt,
                                                   const int4* __restrict__ ovf,
                                                   const unsigned short* __restrict__ hbf,
                                                   const int* __restrict__ indp,
                                                   float* __restrict__ out, int n) {
    long long tid = (long long)blockIdx.x * 256 + threadIdx.x;
    int node = (int)(tid >> 4);
    int li = (int)(tid & 15);
    int lane = threadIdx.x & 63;
    if (node >= n) return;
    const float maskm1 = ((indp[0] < 2) ? 1.0f : 0.0f) - 1.0f;  // MASK=(1,1,0,0)

    int cnt = (int)(packed[node] & 0xffffu);
    int mt = (cnt < MAXDEG) ? cnt : MAXDEG;

    float acc[8];
#pragma unroll
    for (int j = 0; j < 8; ++j) acc[j] = 0.f;
    float rsp = 0.f;
    const int gbase = lane & 48;
    const float2* prow = &pairs[(size_t)node * MAXDEG];

    auto fma8 = [&](float w, uint4 h) {
        acc[0] = fmaf(w, bflo(h.x), acc[0]); acc[1] = fmaf(w, bfhi(h.x), acc[1]);
        acc[2] = fmaf(w, bflo(h.y), acc[2]); acc[3] = fmaf(w, bfhi(h.y), acc[3]);
        acc[4] = fmaf(w, bflo(h.z), acc[4]); acc[5] = fmaf(w, bfhi(h.z), acc[5]);
        acc[6] = fmaf(w, bflo(h.w), acc[6]); acc[7] = fmaf(w, bfhi(h.w), acc[7]);
    };

    for (int base = 0; base < mt; base += 16) {
        int mm = mt - base;
        mm = (mm > 16) ? 16 : mm;
        float wv = 0.f;
        float dv = 0.f;
        if (li < mm) {
            float2 p = prow[base + li];
            dv = p.x;
            int d = __float_as_int(p.x);
            unsigned int pkd = packed[d];
            float deg = (float)(pkd & 0xffffu) + maskm1 * (float)(pkd >> 16);
            wv = deg * p.y;
        }
        rsp += wv;
        int i = 0;
        for (; i + 3 < mm; i += 4) {
            int d0 = __float_as_int(__shfl(dv, gbase + i));
            float w0 = __shfl(wv, gbase + i);
            int d1 = __float_as_int(__shfl(dv, gbase + i + 1));
            float w1 = __shfl(wv, gbase + i + 1);
            int d2 = __float_as_int(__shfl(dv, gbase + i + 2));
            float w2 = __shfl(wv, gbase + i + 2);
            int d3 = __float_as_int(__shfl(dv, gbase + i + 3));
            float w3 = __shfl(wv, gbase + i + 3);
            uint4 h0 = *(const uint4*)&hbf[(size_t)d0 * D + li * 8];
            uint4 h1 = *(const uint4*)&hbf[(size_t)d1 * D + li * 8];
            uint4 h2 = *(const uint4*)&hbf[(size_t)d2 * D + li * 8];
            uint4 h3 = *(const uint4*)&hbf[(size_t)d3 * D + li * 8];
            fma8(w0, h0); fma8(w1, h1); fma8(w2, h2); fma8(w3, h3);
        }
        for (; i + 1 < mm; i += 2) {
            int d0 = __float_as_int(__shfl(dv, gbase + i));
            float w0 = __shfl(wv, gbase + i);
            int d1 = __float_as_int(__shfl(dv, gbase + i + 1));
            float w1 = __shfl(wv, gbase + i + 1);
            uint4 h0 = *(const uint4*)&hbf[(size_t)d0 * D + li * 8];
            uint4 h1 = *(const uint4*)&hbf[(size_t)d1 * D + li * 8];
            fma8(w0, h0); fma8(w1, h1);
        }
        if (i < mm) {
            int d0 = __float_as_int(__shfl(dv, gbase + i));
            float w0 = __shfl(wv, gbase + i);
            uint4 h0 = *(const uint4*)&hbf[(size_t)d0 * D + li * 8];
            fma8(w0, h0);
        }
    }

    // overflow pass (normally empty; exactness fallback)
    int ovn = *ovf_cnt;
    if (ovn > OVF_CAP) ovn = OVF_CAP;
    for (int i = 0; i < ovn; ++i) {
        int4 tq = ovf[i];
        if (tq.x == node) {
            int d = tq.y;
            unsigned int pkd = packed[d];
            float deg = (float)(pkd & 0xffffu) + maskm1 * (float)(pkd >> 16);
            float w = deg * __int_as_float(tq.z);
            if (li == 0) rsp += w;
            uint4 h = *(const uint4*)&hbf[(size_t)d * D + li * 8];
            fma8(w, h);
        }
    }

    rsp += __shfl_xor(rsp, 1);
    rsp += __shfl_xor(rsp, 2);
    rsp += __shfl_xor(rsp, 4);
    rsp += __shfl_xor(rsp, 8);
    rsp = (rsp == 0.f) ? 1.f : rsp;
    float inv = 1.0f / rsp;
    float4 o0, o1;
    o0.x = acc[0] * inv; o0.y = acc[1] * inv; o0.z = acc[2] * inv; o0.w = acc[3] * inv;
    o1.x = acc[4] * inv; o1.y = acc[5] * inv; o1.z = acc[6] * inv; o1.w = acc[7] * inv;
    float* op = &out[(size_t)node * D + li * 8];
    *(float4*)op = o0;
    *(float4*)(op + 4) = o1;
}

extern "C" void kernel_launch(void* const* d_in, const int* in_sizes, int n_in,
                              void* d_out, int out_size, void* d_ws, size_t ws_size,
                              hipStream_t stream) {
    const float* feat   = (const float*)d_in[0];
    const float* W_edge = (const float*)d_in[1];
    const float* W1     = (const float*)d_in[2];
    const float* b1     = (const float*)d_in[3];
    const float* W2     = (const float*)d_in[4];
    const float* b2     = (const float*)d_in[5];
    const int* edge_src = (const int*)d_in[6];
    const int* edge_dst = (const int*)d_in[7];
    const int* indp     = (const int*)d_in[8];

    const int n = in_sizes[0] / D;   // 100000
    const int E = in_sizes[6];       // 600000

    // ws (16B-aligned): Wt1s u16[D*D] | Wt2s u16[D*D] | packed u32[n] | ovf_cnt i32 +pad |
    //                   ovf int4[OVF_CAP] | pairs f2[n*MAXDEG] | hbf u16[n*D]
    char* ws = (char*)d_ws;
    unsigned short* Wt1s = (unsigned short*)ws;
    unsigned short* Wt2s = Wt1s + D * D;
    unsigned int* packed = (unsigned int*)(Wt2s + D * D);
    int* ovf_cnt         = (int*)(packed + n);
    int4* ovf            = (int4*)((char*)ovf_cnt + 16);
    float2* pairs        = (float2*)(ovf + OVF_CAP);
    unsigned short* hbf  = (unsigned short*)(pairs + (size_t)n * MAXDEG);

    // K0: prep W (64 blocks) + zero packed..ovf_cnt (rest)
    const int zbytes = n * 4 + 16;           // packed + ovf_cnt(+pad)
    const int zv4 = zbytes / 16;
    const int zb = (zv4 + 255) / 256;
    k_init<<<64 + zb, 256, 0, stream>>>(W1, W2, Wt1s, Wt2s, (int*)packed, zv4);

    // K1: fused mlp | place
    const int nm = (n + 127) / 128;          // 782
    const int npl = (E + 511) / 512;         // 1172
    k_mlp_place<<<nm + npl, 512, 0, stream>>>(feat, Wt1s, Wt2s, b1, b2, hbf, n, nm, npl,
                                              edge_src, edge_dst, W_edge,
                                              packed, ovf_cnt, ovf, pairs, E);

    // K2: aggregate
    long long athreads = (long long)n * 16;
    k_aggregate<<<(int)((athreads + 255) / 256), 256, 0, stream>>>(packed, pairs, ovf_cnt,
                                                                   ovf, hbf, indp,
                                                                   (float*)d_out, n);
}